// Round 2
// baseline (198.017 us; speedup 1.0000x reference)
//
#include <hip/hip_runtime.h>
#include <hip/hip_cooperative_groups.h>

namespace cg = cooperative_groups;

#define KK 16
#define NPIX 16384   // 128*128

// ws layout (no zero-init required anywhere — harness poisons ws with 0xAA):
//   [0    .. 1023]  : int   maxpart[256]   per-block D2 max, index = b*128 + k*8 + rg
//   [1024 .. 2047]  : float losspart[256]  per-block loss partial sum
//   [4096 .. +2MB]  : int   d2[2*16*16384] squared EDT per (b,k,pixel)

__global__ __launch_bounds__(256) void fused_kernel(const float* __restrict__ pred,
                                                    const int*   __restrict__ mask,
                                                    const float* __restrict__ ign,
                                                    float*       __restrict__ out,
                                                    int*         __restrict__ maxpart,
                                                    float*       __restrict__ losspart,
                                                    int*         __restrict__ d2) {
    __shared__ unsigned char  nuc[NPIX];      // 16 KB
    __shared__ unsigned short sdn[NPIX];      // 32 KB: down-dist, then nd^2 (G2)
    __shared__ unsigned short sup[NPIX];      // 32 KB: up-dist
    __shared__ int   wmax[4];
    __shared__ float wred[4];
    __shared__ float msq[KK];

    cg::grid_group grid = cg::this_grid();
    const int bid = blockIdx.x;   // 0..255
    const int t   = threadIdx.x;  // 0..255

    // ================= Phase 1: exact integer EDT for (b,k), rows rg*16..+15 ==========
    const int b1 = bid >> 7;          // 0..1
    const int k1 = (bid >> 3) & 15;   // 0..15
    const int rg = bid & 7;           // 0..7
    {
        const int label = k1 + 1;
        const int4* m4 = (const int4*)(mask + b1 * NPIX);
        #pragma unroll
        for (int it = 0; it < 16; ++it) {
            const int idx = t + 256 * it;      // 0..4095
            const int4 v = m4[idx];
            uchar4 u;
            u.x = (v.x == label); u.y = (v.y == label);
            u.z = (v.z == label); u.w = (v.w == label);
            *(uchar4*)&nuc[idx * 4] = u;
        }
        __syncthreads();

        // Concurrent down/up 1D column scans (independent serial chains, sentinel 200).
        if (t < 128) {
            const int j = t;
            int dist = 200;
            for (int i = 0; i < 128; ++i) {
                dist = nuc[i * 128 + j] ? min(dist + 1, 200) : 0;
                sdn[i * 128 + j] = (unsigned short)dist;
            }
        } else {
            const int j = t - 128;
            int dist = 200;
            for (int i = 127; i >= 0; --i) {
                dist = nuc[i * 128 + j] ? min(dist + 1, 200) : 0;
                sup[i * 128 + j] = (unsigned short)dist;
            }
        }
        __syncthreads();

        // Combine: G2 = min(down,up)^2  (<= 40000, fits u16; real candidates <= 32258)
        #pragma unroll
        for (int it = 0; it < 64; ++it) {
            const int idx = t + 256 * it;
            const int nd = min((int)sdn[idx], (int)sup[idx]);
            sdn[idx] = (unsigned short)(nd * nd);
        }
        __syncthreads();

        // Row pass: D2[j] = min_jp( G2[jp] + (j-jp)^2 ), 8 consecutive cols / thread
        const int row = rg * 16 + (t >> 4);
        const int c0  = (t & 15) * 8;
        const unsigned short* grow = &sdn[row * 128];
        int best[8];
        #pragma unroll
        for (int u = 0; u < 8; ++u) best[u] = 0x7fffffff;
        for (int jp = 0; jp < 128; ++jp) {
            const int g = (int)grow[jp];
            #pragma unroll
            for (int u = 0; u < 8; ++u) {
                const int dj = c0 + u - jp;
                best[u] = min(best[u], g + dj * dj);
            }
        }
        int* drow = d2 + (b1 * KK + k1) * NPIX + row * 128 + c0;
        *(int4*)drow       = make_int4(best[0], best[1], best[2], best[3]);
        *((int4*)drow + 1) = make_int4(best[4], best[5], best[6], best[7]);

        int bm = 0;
        #pragma unroll
        for (int u = 0; u < 8; ++u) bm = max(bm, best[u]);
        #pragma unroll
        for (int off = 32; off; off >>= 1) bm = max(bm, __shfl_down(bm, off, 64));
        if ((t & 63) == 0) wmax[t >> 6] = bm;
        __syncthreads();
        if (t == 0)
            maxpart[bid] = max(max(wmax[0], wmax[1]), max(wmax[2], wmax[3]));
    }

    __threadfence();
    grid.sync();

    // ================= Phase 2: gt_sonnet + smooth-L1 partial per block ===============
    {
        const int b2 = bid >> 7;   // this block's 128 pixels share one b

        // msq[k] = sqrt(max D2) for this b (reduce 8 row-group partials)
        if (t < KK) {
            const int base = b2 * 128 + t * 8;
            int mt = 0;
            #pragma unroll
            for (int r = 0; r < 8; ++r) mt = max(mt, maxpart[base + r]);
            msq[t] = __fsqrt_rn((float)mt);
        }
        __syncthreads();

        float contrib = 0.0f;
        if (t < 128) {
            const int p  = bid * 128 + t;      // global pixel 0..32767
            const int pp = p & (NPIX - 1);

            float gt[8];
            #pragma unroll
            for (int c = 0; c < 8; ++c) gt[c] = 0.0f;
            const float ddd[8] = {0.83f, 0.68f, 0.54f, 0.41f, 0.29f, 0.18f, 0.09f, 0.0f};

            for (int k = 0; k < KK; ++k) {
                const int D2 = d2[(b2 * KK + k) * NPIX + pp];
                if (D2 >= 1) {
                    const float d  = __fsqrt_rn((float)D2);
                    float dn = __fdiv_rn(d, msq[k]);
                    if (dn < 0.5f) dn = 0.0f;
                    if (dn > 0.7f) dn = 1.0f;
                    #pragma unroll
                    for (int c = 0; c < 8; ++c) {
                        if (dn >= ddd[c]) { gt[c] += 1.0f; break; }
                    }
                }
            }

            float lsum = 0.0f;
            #pragma unroll
            for (int c = 0; c < 8; ++c) {
                const float g = gt[c];
                out[1 + (b2 * 8 + c) * NPIX + pp] = g;
                const float diff = pred[(b2 * 8 + c) * NPIX + pp] - g;
                const float ad = fabsf(diff);
                lsum += (ad < 1.0f) ? 0.5f * diff * diff : (ad - 0.5f);
            }
            contrib = lsum * 0.125f * ign[p];
        }

        #pragma unroll
        for (int off = 32; off; off >>= 1) contrib += __shfl_down(contrib, off, 64);
        if ((t & 63) == 0) wred[t >> 6] = contrib;
        __syncthreads();
        if (t == 0)
            losspart[bid] = (wred[0] + wred[1]) + (wred[2] + wred[3]);
    }

    __threadfence();
    grid.sync();

    // ================= Phase 3: block 0 reduces 256 loss partials =====================
    if (bid == 0) {
        float v = losspart[t];
        #pragma unroll
        for (int off = 32; off; off >>= 1) v += __shfl_down(v, off, 64);
        if ((t & 63) == 0) wred[t >> 6] = v;
        __syncthreads();
        if (t == 0)
            out[0] = ((wred[0] + wred[1]) + (wred[2] + wred[3])) * (1.0f / 32768.0f);
    }
}

extern "C" void kernel_launch(void* const* d_in, const int* in_sizes, int n_in,
                              void* d_out, int out_size, void* d_ws, size_t ws_size,
                              hipStream_t stream) {
    const float* pred = (const float*)d_in[0];
    const int*   mask = (const int*)d_in[1];
    const float* ign  = (const float*)d_in[2];
    float* out = (float*)d_out;

    int*   maxpart  = (int*)d_ws;
    float* losspart = (float*)((char*)d_ws + 1024);
    int*   d2       = (int*)((char*)d_ws + 4096);

    void* args[] = {(void*)&pred, (void*)&mask, (void*)&ign, (void*)&out,
                    (void*)&maxpart, (void*)&losspart, (void*)&d2};
    hipLaunchCooperativeKernel((const void*)fused_kernel, dim3(256), dim3(256),
                               args, 0, stream);
}

// Round 3
// 88.039 us; speedup vs baseline: 2.2492x; 2.2492x over previous
//
#include <hip/hip_runtime.h>

#define KK 16
#define NPIX 16384   // 128*128

// ws layout (no zero-init required — K1 initializes acc/cnt, partials are overwritten):
//   [0    .. 1023]  : int   maxpart[256]   per-block D2 max, index = b*128 + k*8 + rg
//   [1024 .. 1027]  : float acc            loss accumulator   (K1 inits to 0)
//   [1028 .. 1031]  : uint  cnt            ticket counter     (K1 inits to 0)
//   [4096 .. +2MB]  : int   d2[2*16*16384] squared EDT per (b,k,pixel)

__global__ __launch_bounds__(256) void edt_kernel(const int* __restrict__ mask,
                                                  int* __restrict__ maxpart,
                                                  float* __restrict__ acc,
                                                  unsigned int* __restrict__ cnt,
                                                  int* __restrict__ d2) {
    __shared__ unsigned char  nuc[NPIX];      // 16 KB
    __shared__ unsigned short sdn[NPIX];      // 32 KB: down-dist, then nd^2 (G2)
    __shared__ unsigned short sup[NPIX];      // 32 KB: up-dist
    __shared__ int wmax[4];

    const int bid = blockIdx.x;       // 0..255
    const int t   = threadIdx.x;      // 0..255
    const int b1  = bid >> 7;         // 0..1
    const int k1  = (bid >> 3) & 15;  // 0..15
    const int rg  = bid & 7;          // 0..7

    if (bid == 0 && t == 0) { *acc = 0.0f; *cnt = 0u; }  // init for K2 (kernel
                                                         // boundary = visibility)

    // ---- stage nuclei bytes (int4 mask loads) ----
    const int label = k1 + 1;
    const int4* m4 = (const int4*)(mask + b1 * NPIX);
    #pragma unroll
    for (int it = 0; it < 16; ++it) {
        const int idx = t + 256 * it;          // 0..4095
        const int4 v = m4[idx];
        uchar4 u;
        u.x = (v.x == label); u.y = (v.y == label);
        u.z = (v.z == label); u.w = (v.w == label);
        *(uchar4*)&nuc[idx * 4] = u;
    }
    __syncthreads();

    // ---- concurrent down/up 1D column scans (sentinel 200) ----
    if (t < 128) {
        const int j = t;
        int dist = 200;
        for (int i = 0; i < 128; ++i) {
            dist = nuc[i * 128 + j] ? min(dist + 1, 200) : 0;
            sdn[i * 128 + j] = (unsigned short)dist;
        }
    } else {
        const int j = t - 128;
        int dist = 200;
        for (int i = 127; i >= 0; --i) {
            dist = nuc[i * 128 + j] ? min(dist + 1, 200) : 0;
            sup[i * 128 + j] = (unsigned short)dist;
        }
    }
    __syncthreads();

    // ---- combine: G2 = min(down,up)^2 (fits u16) ----
    #pragma unroll
    for (int it = 0; it < 64; ++it) {
        const int idx = t + 256 * it;
        const int nd = min((int)sdn[idx], (int)sup[idx]);
        sdn[idx] = (unsigned short)(nd * nd);
    }
    __syncthreads();

    // ---- row pass: D2[j] = min_jp( G2[jp] + (j-jp)^2 ), 8 consecutive cols/thread ----
    const int row = rg * 16 + (t >> 4);
    const int c0  = (t & 15) * 8;
    const unsigned short* grow = &sdn[row * 128];
    int best[8];
    #pragma unroll
    for (int u = 0; u < 8; ++u) best[u] = 0x7fffffff;
    for (int jp = 0; jp < 128; ++jp) {
        const int g = (int)grow[jp];
        #pragma unroll
        for (int u = 0; u < 8; ++u) {
            const int dj = c0 + u - jp;
            best[u] = min(best[u], g + dj * dj);
        }
    }
    int* drow = d2 + (b1 * KK + k1) * NPIX + row * 128 + c0;
    *(int4*)drow       = make_int4(best[0], best[1], best[2], best[3]);
    *((int4*)drow + 1) = make_int4(best[4], best[5], best[6], best[7]);

    int bm = 0;
    #pragma unroll
    for (int u = 0; u < 8; ++u) bm = max(bm, best[u]);
    #pragma unroll
    for (int off = 32; off; off >>= 1) bm = max(bm, __shfl_down(bm, off, 64));
    if ((t & 63) == 0) wmax[t >> 6] = bm;
    __syncthreads();
    if (t == 0)
        maxpart[bid] = max(max(wmax[0], wmax[1]), max(wmax[2], wmax[3]));
}

__global__ __launch_bounds__(128) void gt_loss_kernel(const float* __restrict__ pred,
                                                      const float* __restrict__ ign,
                                                      const int* __restrict__ d2,
                                                      const int* __restrict__ maxpart,
                                                      float* __restrict__ out,
                                                      float* __restrict__ acc,
                                                      unsigned int* __restrict__ cnt) {
    __shared__ float msq[KK];
    __shared__ float wred[2];

    const int bid = blockIdx.x;           // 0..255
    const int t   = threadIdx.x;          // 0..127
    const int p   = bid * 128 + t;        // global pixel 0..32767
    const int b2  = bid >> 7;             // 0..1
    const int pp  = p & (NPIX - 1);

    // msq[k] = sqrt(max D2) for this b (reduce the 8 row-group partials)
    if (t < KK) {
        const int base = b2 * 128 + t * 8;
        int mt = 0;
        #pragma unroll
        for (int r = 0; r < 8; ++r) mt = max(mt, maxpart[base + r]);
        msq[t] = __fsqrt_rn((float)mt);
    }
    __syncthreads();

    float gt[8];
    #pragma unroll
    for (int c = 0; c < 8; ++c) gt[c] = 0.0f;
    const float ddd[8] = {0.83f, 0.68f, 0.54f, 0.41f, 0.29f, 0.18f, 0.09f, 0.0f};

    for (int k = 0; k < KK; ++k) {
        const int D2 = d2[(b2 * KK + k) * NPIX + pp];
        if (D2 >= 1) {                        // nuclei pixel for this k
            const float d  = __fsqrt_rn((float)D2);
            float dn = __fdiv_rn(d, msq[k]);  // msq>0 since D2>=1
            if (dn < 0.5f) dn = 0.0f;
            if (dn > 0.7f) dn = 1.0f;
            #pragma unroll
            for (int c = 0; c < 8; ++c) {
                if (dn >= ddd[c]) { gt[c] += 1.0f; break; }
            }
        }
    }

    float lsum = 0.0f;
    #pragma unroll
    for (int c = 0; c < 8; ++c) {
        const float g = gt[c];
        out[1 + (b2 * 8 + c) * NPIX + pp] = g;
        const float diff = pred[(b2 * 8 + c) * NPIX + pp] - g;
        const float ad = fabsf(diff);
        lsum += (ad < 1.0f) ? 0.5f * diff * diff : (ad - 0.5f);
    }
    float contrib = lsum * 0.125f * ign[p];

    #pragma unroll
    for (int off = 32; off; off >>= 1) contrib += __shfl_down(contrib, off, 64);
    if ((t & 63) == 0) wred[t >> 6] = contrib;
    __syncthreads();

    if (t == 0) {
        atomicAdd(acc, wred[0] + wred[1]);
        __threadfence();
        const unsigned int old = atomicAdd(cnt, 1u);
        if (old == 255u) {                        // last block: all adds visible
            const float total = atomicAdd(acc, 0.0f);
            out[0] = total * (1.0f / 32768.0f);
        }
    }
}

extern "C" void kernel_launch(void* const* d_in, const int* in_sizes, int n_in,
                              void* d_out, int out_size, void* d_ws, size_t ws_size,
                              hipStream_t stream) {
    const float* pred = (const float*)d_in[0];
    const int*   mask = (const int*)d_in[1];
    const float* ign  = (const float*)d_in[2];
    float* out = (float*)d_out;

    int*          maxpart = (int*)d_ws;
    float*        acc     = (float*)((char*)d_ws + 1024);
    unsigned int* cnt     = (unsigned int*)((char*)d_ws + 1028);
    int*          d2      = (int*)((char*)d_ws + 4096);

    edt_kernel<<<256, 256, 0, stream>>>(mask, maxpart, acc, cnt, d2);
    gt_loss_kernel<<<256, 128, 0, stream>>>(pred, ign, d2, maxpart, out, acc, cnt);
}

// Round 4
// 78.870 us; speedup vs baseline: 2.5107x; 1.1162x over previous
//
#include <hip/hip_runtime.h>

#define KK 16
#define NPIX 16384   // 128*128

// ws layout (no zero-init required — K1 initializes acc/cnt, partials are overwritten):
//   [0    .. 1023]  : int    maxpart[256]  per-block D2 max, index = b*128 + k*8 + rg
//   [1024 .. 1027]  : float  acc           loss accumulator   (K1 inits to 0)
//   [1028 .. 1031]  : uint   cnt           ticket counter     (K1 inits to 0)
//   [4096 .. +1MB]  : u16    d2[2*16*16384] squared EDT per (b,k,pixel), <= 40000

__global__ __launch_bounds__(256) void edt_kernel(const int* __restrict__ mask,
                                                  int* __restrict__ maxpart,
                                                  float* __restrict__ acc,
                                                  unsigned int* __restrict__ cnt,
                                                  unsigned short* __restrict__ d2) {
    __shared__ unsigned char  nuc[NPIX];      // 16 KB
    __shared__ unsigned short sdn[NPIX];      // 32 KB: down-dist, then nd^2 (G2)
    __shared__ unsigned short sup[NPIX];      // 32 KB: up-dist
    __shared__ int wmax[4];

    const int bid = blockIdx.x;       // 0..255
    const int t   = threadIdx.x;      // 0..255
    const int b1  = bid >> 7;         // 0..1
    const int k1  = (bid >> 3) & 15;  // 0..15
    const int rg  = bid & 7;          // 0..7

    if (bid == 0 && t == 0) { *acc = 0.0f; *cnt = 0u; }  // init for K2
                                                         // (kernel boundary = visibility)

    // ---- stage nuclei bytes (int4 mask loads) ----
    const int label = k1 + 1;
    const int4* m4 = (const int4*)(mask + b1 * NPIX);
    #pragma unroll
    for (int it = 0; it < 16; ++it) {
        const int idx = t + 256 * it;          // 0..4095
        const int4 v = m4[idx];
        uchar4 u;
        u.x = (v.x == label); u.y = (v.y == label);
        u.z = (v.z == label); u.w = (v.w == label);
        *(uchar4*)&nuc[idx * 4] = u;
    }
    __syncthreads();

    // ---- concurrent down/up 1D column scans (sentinel 200) ----
    if (t < 128) {
        const int j = t;
        int dist = 200;
        for (int i = 0; i < 128; ++i) {
            dist = nuc[i * 128 + j] ? min(dist + 1, 200) : 0;
            sdn[i * 128 + j] = (unsigned short)dist;
        }
    } else {
        const int j = t - 128;
        int dist = 200;
        for (int i = 127; i >= 0; --i) {
            dist = nuc[i * 128 + j] ? min(dist + 1, 200) : 0;
            sup[i * 128 + j] = (unsigned short)dist;
        }
    }
    __syncthreads();

    // ---- combine: G2 = min(down,up)^2 (<= 40000, fits u16) ----
    #pragma unroll
    for (int it = 0; it < 64; ++it) {
        const int idx = t + 256 * it;
        const int nd = min((int)sdn[idx], (int)sup[idx]);
        sdn[idx] = (unsigned short)(nd * nd);
    }
    __syncthreads();

    // ---- row pass: D2[j] = min_jp( G2[jp] + (j-jp)^2 ), 8 consecutive cols/thread ----
    const int row = rg * 16 + (t >> 4);
    const int c0  = (t & 15) * 8;
    const unsigned short* grow = &sdn[row * 128];
    int best[8];
    #pragma unroll
    for (int u = 0; u < 8; ++u) best[u] = 0x7fffffff;
    for (int jp = 0; jp < 128; ++jp) {
        const int g = (int)grow[jp];
        #pragma unroll
        for (int u = 0; u < 8; ++u) {
            const int dj = c0 + u - jp;
            best[u] = min(best[u], g + dj * dj);
        }
    }

    // pack 8 u16 D2 values -> one 16B store (values <= 40000 fit u16)
    uint4 w;
    w.x = (unsigned)best[0] | ((unsigned)best[1] << 16);
    w.y = (unsigned)best[2] | ((unsigned)best[3] << 16);
    w.z = (unsigned)best[4] | ((unsigned)best[5] << 16);
    w.w = (unsigned)best[6] | ((unsigned)best[7] << 16);
    *(uint4*)(d2 + (b1 * KK + k1) * NPIX + row * 128 + c0) = w;

    int bm = 0;
    #pragma unroll
    for (int u = 0; u < 8; ++u) bm = max(bm, best[u]);
    #pragma unroll
    for (int off = 32; off; off >>= 1) bm = max(bm, __shfl_down(bm, off, 64));
    if ((t & 63) == 0) wmax[t >> 6] = bm;
    __syncthreads();
    if (t == 0)
        maxpart[bid] = max(max(wmax[0], wmax[1]), max(wmax[2], wmax[3]));
}

// Disjoint-support gt+loss: each pixel belongs to at most ONE instance (mask is a
// single label per pixel), so gt has exactly one nonzero channel, selected by the
// pixel's own label — no loop over k, one d2 gather per pixel.
__global__ __launch_bounds__(256) void gt_loss_kernel(const float* __restrict__ pred,
                                                      const float* __restrict__ ign,
                                                      const int* __restrict__ mask,
                                                      const unsigned short* __restrict__ d2,
                                                      const int* __restrict__ maxpart,
                                                      float* __restrict__ out,
                                                      float* __restrict__ acc,
                                                      unsigned int* __restrict__ cnt) {
    __shared__ float msq[KK];
    __shared__ float wred[4];

    const int bid = blockIdx.x;           // 0..127
    const int t   = threadIdx.x;          // 0..255
    const int p   = bid * 256 + t;        // global pixel 0..32767
    const int b   = bid >> 6;             // 0..1  (all pixels of a block share b)
    const int pp  = p & (NPIX - 1);

    // msq[k] = sqrt(max D2) for this b (reduce the 8 row-group partials)
    if (t < KK) {
        const int base = b * 128 + t * 8;
        int mt = 0;
        #pragma unroll
        for (int r = 0; r < 8; ++r) mt = max(mt, maxpart[base + r]);
        msq[t] = __fsqrt_rn((float)mt);
    }
    __syncthreads();

    const int label = mask[p];
    int cbin = -1;                        // which gt channel is 1 (none if bg)
    if (label > 0) {
        const int k = label - 1;
        const float d  = __fsqrt_rn((float)d2[(b * KK + k) * NPIX + pp]);  // D2>=1
        float dn = __fdiv_rn(d, msq[k]);  // msq >= 1 since maxD2 >= D2 >= 1
        if (dn < 0.5f) dn = 0.0f;
        if (dn > 0.7f) dn = 1.0f;
        const float ddd[8] = {0.83f, 0.68f, 0.54f, 0.41f, 0.29f, 0.18f, 0.09f, 0.0f};
        #pragma unroll
        for (int c = 0; c < 8; ++c) {
            if (cbin < 0 && dn >= ddd[c]) cbin = c;
        }
    }

    float lsum = 0.0f;
    #pragma unroll
    for (int c = 0; c < 8; ++c) {
        const float g = (c == cbin) ? 1.0f : 0.0f;
        out[1 + (b * 8 + c) * NPIX + pp] = g;
        const float diff = pred[(b * 8 + c) * NPIX + pp] - g;
        const float ad = fabsf(diff);
        lsum += (ad < 1.0f) ? 0.5f * diff * diff : (ad - 0.5f);
    }
    float contrib = lsum * 0.125f * ign[p];

    #pragma unroll
    for (int off = 32; off; off >>= 1) contrib += __shfl_down(contrib, off, 64);
    if ((t & 63) == 0) wred[t >> 6] = contrib;
    __syncthreads();

    if (t == 0) {
        atomicAdd(acc, (wred[0] + wred[1]) + (wred[2] + wred[3]));
        __threadfence();
        const unsigned int old = atomicAdd(cnt, 1u);
        if (old == 127u) {                        // last block: all adds visible
            const float total = atomicAdd(acc, 0.0f);
            out[0] = total * (1.0f / 32768.0f);
        }
    }
}

extern "C" void kernel_launch(void* const* d_in, const int* in_sizes, int n_in,
                              void* d_out, int out_size, void* d_ws, size_t ws_size,
                              hipStream_t stream) {
    const float* pred = (const float*)d_in[0];
    const int*   mask = (const int*)d_in[1];
    const float* ign  = (const float*)d_in[2];
    float* out = (float*)d_out;

    int*            maxpart = (int*)d_ws;
    float*          acc     = (float*)((char*)d_ws + 1024);
    unsigned int*   cnt     = (unsigned int*)((char*)d_ws + 1028);
    unsigned short* d2      = (unsigned short*)((char*)d_ws + 4096);

    edt_kernel<<<256, 256, 0, stream>>>(mask, maxpart, acc, cnt, d2);
    gt_loss_kernel<<<128, 256, 0, stream>>>(pred, ign, mask, d2, maxpart, out, acc, cnt);
}